// Round 10
// baseline (210.442 us; speedup 1.0000x reference)
//
#include <hip/hip_runtime.h>
#include <hip/hip_fp16.h>

// Problem constants (fixed shapes from setup_inputs)
#define B_ 4
#define T_ 512
#define C_ 8
#define F_ 257
#define TAPS 5
#define DELAY 3
#define N_ 40          // TAPS*C
#define NA 48          // N_ + C_ (augmented: R | P)
#define TP 505         // T - DELAY - TAPS + 1
#define T0 7           // DELAY + TAPS - 1
#define BF (B_*F_)     // 1028
#define BTCF ((size_t)B_*T_*C_*F_)
#define YSH 532        // padded LDS row stride (f16x2 dwords)
#define YPAD 8         // leading zero pad (t stored at index t+YPAD)
#define AUGSZ 1180     // packed upper-tri: sum_{i<40}(49-i) float2
#define ZSD 36         // sZT dword stride per t-row (72 f16; 16B-aligned)

typedef _Float16 half8 __attribute__((ext_vector_type(8)));
typedef float floatx4 __attribute__((ext_vector_type(4)));
typedef uint32_t uint32x4 __attribute__((ext_vector_type(4)));

__device__ inline uint32_t h2mul(uint32_t a, uint32_t b) {
    __half2 r = __hmul2(__builtin_bit_cast(__half2, a), __builtin_bit_cast(__half2, b));
    return __builtin_bit_cast(uint32_t, r);
}
__device__ inline uint32_t packf16(float2 v) {
    __half2 h = __floats2half2_rn(v.x, v.y);
    return __builtin_bit_cast(uint32_t, h);
}
__device__ inline half8 mkfrag(uint32_t a, uint32_t b, uint32_t c, uint32_t d) {
    uint32x4 v = {a, b, c, d};
    return __builtin_bit_cast(half8, v);
}
// packed upper-triangle row start: row i holds cols i..47 (+1 pad) -> 49-i entries
__device__ inline int rowoff(int i) {
    return i * 49 - ((i * (i - 1)) >> 1);
}

struct Frag { half8 X; half8 Y; };

// Build weighted re (X) / im (Y) f16 fragments from 8 consecutive interleaved
// f16x2 dwords at p, scaled by packed f16 weight pairs sw0..3. Pure value flow.
__device__ inline Frag build2(const uint32_t* p, uint32_t sw0, uint32_t sw1,
                              uint32_t sw2, uint32_t sw3) {
    uint32_t q0 = p[0], q1 = p[1], q2 = p[2], q3 = p[3];
    uint32_t q4 = p[4], q5 = p[5], q6 = p[6], q7 = p[7];
    uint32_t x0 = __builtin_amdgcn_perm(q1, q0, 0x05040100);
    uint32_t y0 = __builtin_amdgcn_perm(q1, q0, 0x07060302);
    uint32_t x1 = __builtin_amdgcn_perm(q3, q2, 0x05040100);
    uint32_t y1 = __builtin_amdgcn_perm(q3, q2, 0x07060302);
    uint32_t x2 = __builtin_amdgcn_perm(q5, q4, 0x05040100);
    uint32_t y2 = __builtin_amdgcn_perm(q5, q4, 0x07060302);
    uint32_t x3 = __builtin_amdgcn_perm(q7, q6, 0x05040100);
    uint32_t y3 = __builtin_amdgcn_perm(q7, q6, 0x07060302);
    Frag f;
    f.X = mkfrag(h2mul(x0, sw0), h2mul(x1, sw1), h2mul(x2, sw2), h2mul(x3, sw3));
    f.Y = mkfrag(h2mul(y0, sw0), h2mul(y1, sw1), h2mul(y2, sw2), h2mul(y3, sw3));
    return f;
}
// Zs row j -> dword offset into sYh (t stored at t+YPAD):
// j<40: tap=j>>3,c=j&7 -> Y[c][k+4-tap]; j>=40: Y[j-40][k+7]
__device__ inline int zs_off(int j) {
    return (j < N_) ? (j & 7) * YSH + (YPAD + 4 - (j >> 3)) : (j - N_) * YSH + (YPAD + T0);
}

// ---------------- Fully fused single kernel: planar read -> power -> MFMA Gram
//                  -> Hermitian packed solve -> MFMA tail -> masked planar write.
// The former K1/K3 transposes (85-97 us combined, stuck at 4x roofline because
// F=257 forbids any vector alignment on the planar side) and the 33.7MB Y
// workspace (2x67MB extra HBM round-trips) are deleted. Coalescing is replaced
// by XCD-grouped line sharing: with 5 blocks/CU the ~129 blocks of an XCD are
// ALL co-resident, so the ~16 blocks (consecutive f, same b) sharing each 64B
// planar line run concurrently on the same XCD's L2 -> each line is fetched
// once and write-combined once. Swizzle is the m204 bijective variant
// (nwg=1028, q=128, r=4); correctness never depends on the XCD mapping.
__global__ __launch_bounds__(256) void k_fused(const float* __restrict__ in_re,
                                               const float* __restrict__ in_im,
                                               const int* __restrict__ ilens,
                                               float* __restrict__ out_re,
                                               float* __restrict__ out_im,
                                               float* __restrict__ pow_out) {
    __shared__ uint32_t sYh[C_ * YSH];               // 17024 B f16x2 (re,im), t at t+YPAD
    __shared__ __align__(16) float uScr[640];        //  2560 B: sPow[512] then sGT[320]
    __shared__ __align__(16) uint32_t sw_pk[256];    //  1024 B packed f16 sqrt-weight pairs
    __shared__ __align__(16) float2 sAugU[AUGSZ];    //  9440 B packed upper tri; later sZT
    float* sPow = uScr;                              // live: stage -> weights
    float2* sGT = (float2*)uScr;                     // live: after solve -> tail
    int tid = threadIdx.x;

    // ---- XCD-grouped bijective block swizzle: XCD x (= bid%8 heuristic) gets a
    //      CONTIGUOUS logical range; consecutive w = consecutive f (same b). ----
    int bid = blockIdx.x;
    int xcd = bid & 7, slot = bid >> 3;
    int w = (xcd < 4) ? xcd * 129 + slot : 516 + (xcd - 4) * 128 + slot;
    int b = w / F_;                 // magic-mul (constant divisor)
    int f = w - b * F_;
    int ilen = ilens[b];
    const float* pre = in_re + (size_t)b * T_ * C_ * F_ + f;
    const float* pim = in_im + (size_t)b * T_ * C_ * F_ + f;

    // ---- stage: planar scalar 4B reads (line-shared across same-XCD f-neighbors),
    //      f16x2 LDS writes, fp32 power. unroll 2 caps live loads. ----
    {
        int t0 = tid, t1 = tid + 256;
        float s0 = 0.f, s1 = 0.f;
#pragma unroll 2
        for (int c = 0; c < C_; ++c) {
            size_t a0 = ((size_t)t0 * C_ + c) * F_;
            size_t a1 = ((size_t)t1 * C_ + c) * F_;
            float xr0 = pre[a0], xi0 = pim[a0];
            float xr1 = pre[a1], xi1 = pim[a1];
            sYh[c * YSH + YPAD + t0] = packf16(make_float2(xr0, xi0));
            sYh[c * YSH + YPAD + t1] = packf16(make_float2(xr1, xi1));
            s0 += xr0 * xr0 + xi0 * xi0;
            s1 += xr1 * xr1 + xi1 * xi1;
        }
        if (tid < 20) {
            int z = (tid < 8) ? tid : (512 + tid);   // [0..7] and [520..531]
#pragma unroll
            for (int c = 0; c < C_; ++c) sYh[c * YSH + z] = 0;
        }
        s0 = fmaxf(s0 * (1.0f / C_), 1e-6f);
        s1 = fmaxf(s1 * (1.0f / C_), 1e-6f);
        pow_out[(size_t)w * T_ + t0] = s0;           // (B,F,T), coalesced
        pow_out[(size_t)w * T_ + t1] = s1;
        sPow[t0] = s0;
        sPow[t1] = s1;
    }
    __syncthreads();

    // ---- packed f16 sqrt(1/p[k+7]) weight pairs; zero for k >= TP (pads K to 512) ----
    {
        int k0 = 2 * tid, k1 = k0 + 1;
        float w0 = (k0 < TP) ? rsqrtf(sPow[k0 + T0]) : 0.f;   // p >= 1e-6 so max(p,1e-10)=p
        float w1 = (k1 < TP) ? rsqrtf(sPow[k1 + T0]) : 0.f;
        sw_pk[tid] = packf16(make_float2(w0, w1));
    }
    __syncthreads();

    // ---- Gram via MFMA: G = Zs^H Zs (48x48, K=512). Wave wv owns 16-col strip.
    //      Hermitian: keep only upper triangle (col >= m) incl. RHS cols 40..47. ----
    int wv = tid >> 6, ln = tid & 63;
    int kg = ln >> 4;            // 16-lane group (k-slice selector for MFMA frags)
    if (wv < 3) {
        int r16 = ln & 15;
        int offB = zs_off(wv * 16 + r16);
#pragma unroll 1
        for (int mt = 0; mt < 3; ++mt) {
            int offA = zs_off(mt * 16 + r16);
            floatx4 aRe = {0.f, 0.f, 0.f, 0.f};
            floatx4 aIm = {0.f, 0.f, 0.f, 0.f};
#pragma unroll 2
            for (int ks = 0; ks < 16; ++ks) {
                int kbase = ks * 32 + kg * 8;
                uint32x4 sv = *(const uint32x4*)&sw_pk[kbase >> 1];
                Frag B = build2(&sYh[offB + kbase], sv[0], sv[1], sv[2], sv[3]);
                Frag A = build2(&sYh[offA + kbase], sv[0], sv[1], sv[2], sv[3]);
                half8 nYa = -A.Y;
                aRe = __builtin_amdgcn_mfma_f32_16x16x32_f16(A.X, B.X, aRe, 0, 0, 0);
                aRe = __builtin_amdgcn_mfma_f32_16x16x32_f16(A.Y, B.Y, aRe, 0, 0, 0);
                aIm = __builtin_amdgcn_mfma_f32_16x16x32_f16(A.X, B.Y, aIm, 0, 0, 0);
                aIm = __builtin_amdgcn_mfma_f32_16x16x32_f16(nYa, B.X, aIm, 0, 0, 0);
            }
            // C/D layout: col = lane&15, row = (lane>>4)*4 + reg  [m89-verified]
#pragma unroll
            for (int r = 0; r < 4; ++r) {
                int m = mt * 16 + kg * 4 + r;
                int col = wv * 16 + r16;
                if (m < N_ && col >= m)
                    sAugU[rowoff(m) + col - m] = make_float2(aRe[r], aIm[r]);
            }
        }
    }
    __syncthreads();

    // ---- diag loading: wave-parallel trace reduce ----
    if (tid < 64) {
        float dv = (tid < N_) ? sAugU[rowoff(tid)].x : 0.f;
#pragma unroll
        for (int off = 32; off; off >>= 1) dv += __shfl_xor(dv, off, 64);
        if (tid < N_) sAugU[rowoff(tid)].x += 1e-10f * dv / N_;
    }
    __syncthreads();

    // ---- forward elimination on packed upper triangle (Hermitian, half work).
    //      m_i = conj(A[p][i]) * inv_p  ==  A[i][p] * inv_p  exactly. ----
    {
        int ri = tid >> 4, ci = tid & 15;
#pragma unroll 1
        for (int p = 0; p < N_ - 1; ++p) {
            int rop = rowoff(p);
            float2 piv = sAugU[rop];
            float dnm = piv.x * piv.x + piv.y * piv.y;
            float pix = piv.x / dnm, piy = -piv.y / dnm;
#pragma unroll 1
            for (int i = p + 1 + ri; i < N_; i += 16) {
                float2 api = sAugU[rop + i - p];       // A[p][i]
                float mx = api.x * pix + api.y * piy;  // conj(api)*inv
                float my = api.x * piy - api.y * pix;
                int roi = rowoff(i) - i;               // + j gives addr
#pragma unroll 1
                for (int j = i + ci; j < NA; j += 16) {
                    float2 apj = sAugU[rop + j - p];
                    float2 v = sAugU[roi + j];
                    v.x -= mx * apj.x - my * apj.y;
                    v.y -= mx * apj.y + my * apj.x;
                    sAugU[roi + j] = v;
                }
            }
            __syncthreads();
        }
    }
    // ---- backward elimination on RHS columns (i<p reads (i,p): upper ✓) ----
    {
        int bc = tid & 7, br = tid >> 3;
#pragma unroll 1
        for (int p = N_ - 1; p > 0; --p) {
            int rop = rowoff(p);
            float2 piv = sAugU[rop];
            float dnm = piv.x * piv.x + piv.y * piv.y;
            float pix = piv.x / dnm, piy = -piv.y / dnm;
            float2 rhs = sAugU[rop + N_ + bc - p];
            float xr = rhs.x * pix - rhs.y * piy;
            float xi = rhs.x * piy + rhs.y * pix;
#pragma unroll 1
            for (int i = br; i < p; i += 32) {
                int roi = rowoff(i) - i;
                float2 aip = sAugU[roi + p];
                float2 v = sAugU[roi + N_ + bc];
                v.x -= aip.x * xr - aip.y * xi;
                v.y -= aip.x * xi + aip.y * xr;
                sAugU[roi + N_ + bc] = v;
            }
            __syncthreads();
        }
    }
    // ---- G, transposed store: sGT[e][d][tau] = RHS[j=tau*8+d][e] / diag[j].
    //      sGT overlays sPow (dead since weights phase). ----
    for (int idx = tid; idx < N_ * C_; idx += 256) {
        int j = idx >> 3;
        int e = idx & 7;
        int roj = rowoff(j);
        float2 piv = sAugU[roj];
        float dnm = piv.x * piv.x + piv.y * piv.y;
        float pix = piv.x / dnm, piy = -piv.y / dnm;
        float2 rhs = sAugU[roj + N_ + e - j];
        int tau = j >> 3, d = j & 7;
        sGT[(e * C_ + d) * TAPS + tau] =
            make_float2(rhs.x * pix - rhs.y * piy, rhs.x * piy + rhs.y * pix);
    }
    __syncthreads();   // sAugU dead from here -> reuse as sZT planes

    // ================= MFMA tail =================
    // tail[e][t] = sum_j G[j][e] * Zraw[j][t]; direct term re-read fp32 from
    // the planar input (L2/L3-hot after stage); ilens mask applied; planar
    // 4B output writes (line-combined across same-XCD f-neighbors).
    uint32_t* zRe = (uint32_t*)sAugU;                // [32][ZSD] dwords (f16 pairs)
    uint32_t* zIm = zRe + 32 * ZSD;                  // 2*32*36*4 = 9216 B <= 9440
    // A fragments: built once from sGT (f16 cast; G ~O(1), threshold 0.134).
    half8 aFr[2], aFi[2];
    {
        int m = ln & 15;
#pragma unroll
        for (int ks = 0; ks < 2; ++ks) {
            half8 hr = {}, hi = {};
#pragma unroll
            for (int q = 0; q < 8; ++q) {
                int j = ks * 32 + kg * 8 + q;
                float gx = 0.f, gy = 0.f;
                if (m < 8 && j < N_) {
                    float2 g = sGT[(m * C_ + (j & 7)) * TAPS + (j >> 3)];
                    gx = g.x; gy = g.y;
                }
                hr[q] = (_Float16)gx;
                hi[q] = (_Float16)gy;
            }
            aFr[ks] = hr;
            aFi[ks] = hi;
        }
    }
    // zero both planes once (covers k-pad j>=40; builds only write jp<20)
    for (int idx = tid; idx < 2 * 32 * ZSD; idx += 256) zRe[idx] = 0;
    __syncthreads();

#pragma unroll 1
    for (int ch = 0; ch < 16; ++ch) {
        int c0 = ch * 32;
        // build: 20 j-pairs x 32 t (taus are 8-aligned so pairs never cross a
        // tau boundary). sYh idx = (c0+tl) -3-tau + YPAD; zero pad drops s<0.
        for (int idx = tid; idx < 640; idx += 256) {
            int jp = idx >> 5, tl = idx & 31;
            int j0 = 2 * jp, j1 = j0 + 1;
            int base = c0 + tl + (YPAD - 3);
            uint32_t y0 = sYh[(j0 & 7) * YSH + base - (j0 >> 3)];
            uint32_t y1 = sYh[(j1 & 7) * YSH + base - (j1 >> 3)];
            zRe[tl * ZSD + jp] = __builtin_amdgcn_perm(y1, y0, 0x05040100);
            zIm[tl * ZSD + jp] = __builtin_amdgcn_perm(y1, y0, 0x07060302);
        }
        __syncthreads();
        if (wv < 2) {   // wave wv owns t-tile wv of this chunk; waves 2,3 idle here
            floatx4 accR = {0.f, 0.f, 0.f, 0.f};
            floatx4 accI = {0.f, 0.f, 0.f, 0.f};
            int trow = wv * 16 + (ln & 15);
#pragma unroll
            for (int ks = 0; ks < 2; ++ks) {
                int o = trow * ZSD + ks * 16 + kg * 4;
                half8 Br = __builtin_bit_cast(half8, *(const uint32x4*)&zRe[o]);
                half8 Bi = __builtin_bit_cast(half8, *(const uint32x4*)&zIm[o]);
                half8 nFi = -aFi[ks];
                accR = __builtin_amdgcn_mfma_f32_16x16x32_f16(aFr[ks], Br, accR, 0, 0, 0);
                accR = __builtin_amdgcn_mfma_f32_16x16x32_f16(nFi, Bi, accR, 0, 0, 0);
                accI = __builtin_amdgcn_mfma_f32_16x16x32_f16(aFr[ks], Bi, accI, 0, 0, 0);
                accI = __builtin_amdgcn_mfma_f32_16x16x32_f16(aFi[ks], Br, accI, 0, 0, 0);
            }
            if (kg < 2) {    // D rows kg*4+r = e in [0,8); rows 8..15 are zero
                int tg = c0 + trow;
                bool dead = (tg >= ilen);
#pragma unroll
                for (int r = 0; r < 4; ++r) {
                    int e = kg * 4 + r;
                    size_t a = ((size_t)tg * C_ + e) * F_;   // rel. to (b,f) base
                    float ex = pre[a] - accR[r];
                    float ey = pim[a] - accI[r];
                    if (dead) { ex = 0.f; ey = 0.f; }
                    size_t o = (size_t)b * T_ * C_ * F_ + f + a;
                    out_re[o] = ex;
                    out_im[o] = ey;
                }
            }
        }
        __syncthreads();   // WAR: next build overwrites zRe/zIm
    }
}

extern "C" void kernel_launch(void* const* d_in, const int* in_sizes, int n_in,
                              void* d_out, int out_size, void* d_ws, size_t ws_size,
                              hipStream_t stream) {
    const float* in_re = (const float*)d_in[0];
    const float* in_im = (const float*)d_in[1];
    const int* ilens = (const int*)d_in[2];

    float* out_re = (float*)d_out;
    float* out_im = out_re + BTCF;
    float* out_pw = out_im + BTCF;   // (B,F,T) float32

    // Single fused kernel: no transposes, no workspace.
    k_fused<<<BF, 256, 0, stream>>>(in_re, in_im, ilens, out_re, out_im, out_pw);
}

// Round 11
// 189.358 us; speedup vs baseline: 1.1113x; 1.1113x over previous
//
#include <hip/hip_runtime.h>
#include <hip/hip_fp16.h>

// Problem constants (fixed shapes from setup_inputs)
#define B_ 4
#define T_ 512
#define C_ 8
#define F_ 257
#define TAPS 5
#define DELAY 3
#define N_ 40          // TAPS*C
#define NA 48          // N_ + C_ (augmented: R | P)
#define TP 505         // T - DELAY - TAPS + 1
#define T0 7           // DELAY + TAPS - 1
#define BF (B_*F_)     // 1028
#define BTCF ((size_t)B_*T_*C_*F_)
#define YSH 532        // padded LDS row stride (f16x2 dwords)
#define YPAD 8         // leading zero pad (t stored at index t+YPAD)
#define AUGSZ 1180     // packed upper-tri: sum_{i<40}(49-i) float2
#define ZSD 36         // z-plane dword stride per t-row (16B-aligned)

typedef _Float16 half8 __attribute__((ext_vector_type(8)));
typedef float floatx4 __attribute__((ext_vector_type(4)));
typedef uint32_t uint32x4 __attribute__((ext_vector_type(4)));

__device__ inline uint32_t h2mul(uint32_t a, uint32_t b) {
    __half2 r = __hmul2(__builtin_bit_cast(__half2, a), __builtin_bit_cast(__half2, b));
    return __builtin_bit_cast(uint32_t, r);
}
__device__ inline uint32_t packf16(float2 v) {
    __half2 h = __floats2half2_rn(v.x, v.y);
    return __builtin_bit_cast(uint32_t, h);
}
__device__ inline float2 unpackf16(uint32_t u) {
    __half2 h = __builtin_bit_cast(__half2, u);
    return make_float2(__low2float(h), __high2float(h));
}
__device__ inline half8 mkfrag(uint32_t a, uint32_t b, uint32_t c, uint32_t d) {
    uint32x4 v = {a, b, c, d};
    return __builtin_bit_cast(half8, v);
}
// packed upper-triangle row start: row i holds cols i..47 (+1 pad) -> 49-i entries
__device__ inline int rowoff(int i) {
    return i * 49 - ((i * (i - 1)) >> 1);
}

struct Frag { half8 X; half8 Y; };

// Build weighted re (X) / im (Y) f16 fragments from 8 consecutive interleaved
// f16x2 dwords at p, scaled by packed f16 weight pairs sw0..3. Pure value flow.
__device__ inline Frag build2(const uint32_t* p, uint32_t sw0, uint32_t sw1,
                              uint32_t sw2, uint32_t sw3) {
    uint32_t q0 = p[0], q1 = p[1], q2 = p[2], q3 = p[3];
    uint32_t q4 = p[4], q5 = p[5], q6 = p[6], q7 = p[7];
    uint32_t x0 = __builtin_amdgcn_perm(q1, q0, 0x05040100);
    uint32_t y0 = __builtin_amdgcn_perm(q1, q0, 0x07060302);
    uint32_t x1 = __builtin_amdgcn_perm(q3, q2, 0x05040100);
    uint32_t y1 = __builtin_amdgcn_perm(q3, q2, 0x07060302);
    uint32_t x2 = __builtin_amdgcn_perm(q5, q4, 0x05040100);
    uint32_t y2 = __builtin_amdgcn_perm(q5, q4, 0x07060302);
    uint32_t x3 = __builtin_amdgcn_perm(q7, q6, 0x05040100);
    uint32_t y3 = __builtin_amdgcn_perm(q7, q6, 0x07060302);
    Frag f;
    f.X = mkfrag(h2mul(x0, sw0), h2mul(x1, sw1), h2mul(x2, sw2), h2mul(x3, sw3));
    f.Y = mkfrag(h2mul(y0, sw0), h2mul(y1, sw1), h2mul(y2, sw2), h2mul(y3, sw3));
    return f;
}
// Zs row j -> dword offset into sYh (t stored at t+YPAD):
// j<40: tap=j>>3,c=j&7 -> Y[c][k+4-tap]; j>=40: Y[j-40][k+7]
__device__ inline int zs_off(int j) {
    return (j < N_) ? (j & 7) * YSH + (YPAD + 4 - (j >> 3)) : (j - N_) * YSH + (YPAD + T0);
}

// ---------------- Fully fused single kernel: planar read -> power -> MFMA Gram
//                  -> Hermitian packed solve -> MFMA tail -> masked planar write.
// Coalescing via XCD-grouped line sharing (R10-proven: FETCH 46.5MB vs 67
// worst-case, WRITE 1.34x ideal): with 5 blocks/CU all ~129 blocks of an XCD
// are co-resident, so the ~16 blocks (consecutive f, same b) sharing each 64B
// planar line hit the same XCD L2. m204 bijective swizzle (nwg=1028,q=128,r=4).
// R11: tail direct-term from LDS f16 (kills 4096 scattered loads/block),
// 4-wave tail MFMA via single shared z-plane (RE pass then IM pass), stage
// unroll 4 (16 loads in flight). Kernel is latency-bound (R10: 100MB @ 660GB/s
// = 8% peak, VALUBusy 37%) - these attack the stall, not BW.
__global__ __launch_bounds__(256) void k_fused(const float* __restrict__ in_re,
                                               const float* __restrict__ in_im,
                                               const int* __restrict__ ilens,
                                               float* __restrict__ out_re,
                                               float* __restrict__ out_im,
                                               float* __restrict__ pow_out) {
    __shared__ uint32_t sYh[C_ * YSH];               // 17024 B f16x2 (re,im), t at t+YPAD
    __shared__ __align__(16) float uScr[640];        //  2560 B: sPow[512] then sGT[320]
    __shared__ __align__(16) uint32_t sw_pk[256];    //  1024 B packed f16 sqrt-weight pairs
    __shared__ __align__(16) float2 sAugU[AUGSZ];    //  9440 B packed upper tri; later zBuf
    float* sPow = uScr;                              // live: stage -> weights
    float2* sGT = (float2*)uScr;                     // live: after solve -> tail
    int tid = threadIdx.x;

    // ---- XCD-grouped bijective block swizzle ----
    int bid = blockIdx.x;
    int xcd = bid & 7, slot = bid >> 3;
    int w = (xcd < 4) ? xcd * 129 + slot : 516 + (xcd - 4) * 128 + slot;
    int b = w / F_;                 // magic-mul (constant divisor)
    int f = w - b * F_;
    int ilen = ilens[b];
    const float* pre = in_re + (size_t)b * T_ * C_ * F_ + f;
    const float* pim = in_im + (size_t)b * T_ * C_ * F_ + f;

    // ---- stage: planar scalar 4B reads (line-shared across same-XCD f-neighbors),
    //      f16x2 LDS writes, fp32 power. unroll 4: 16 loads in flight. ----
    {
        int t0 = tid, t1 = tid + 256;
        float s0 = 0.f, s1 = 0.f;
#pragma unroll 4
        for (int c = 0; c < C_; ++c) {
            size_t a0 = ((size_t)t0 * C_ + c) * F_;
            size_t a1 = ((size_t)t1 * C_ + c) * F_;
            float xr0 = pre[a0], xi0 = pim[a0];
            float xr1 = pre[a1], xi1 = pim[a1];
            sYh[c * YSH + YPAD + t0] = packf16(make_float2(xr0, xi0));
            sYh[c * YSH + YPAD + t1] = packf16(make_float2(xr1, xi1));
            s0 += xr0 * xr0 + xi0 * xi0;
            s1 += xr1 * xr1 + xi1 * xi1;
        }
        if (tid < 20) {
            int z = (tid < 8) ? tid : (512 + tid);   // [0..7] and [520..531]
#pragma unroll
            for (int c = 0; c < C_; ++c) sYh[c * YSH + z] = 0;
        }
        s0 = fmaxf(s0 * (1.0f / C_), 1e-6f);
        s1 = fmaxf(s1 * (1.0f / C_), 1e-6f);
        pow_out[(size_t)w * T_ + t0] = s0;           // (B,F,T), coalesced
        pow_out[(size_t)w * T_ + t1] = s1;
        sPow[t0] = s0;
        sPow[t1] = s1;
    }
    __syncthreads();

    // ---- packed f16 sqrt(1/p[k+7]) weight pairs; zero for k >= TP (pads K to 512) ----
    {
        int k0 = 2 * tid, k1 = k0 + 1;
        float w0 = (k0 < TP) ? rsqrtf(sPow[k0 + T0]) : 0.f;   // p >= 1e-6 so max(p,1e-10)=p
        float w1 = (k1 < TP) ? rsqrtf(sPow[k1 + T0]) : 0.f;
        sw_pk[tid] = packf16(make_float2(w0, w1));
    }
    __syncthreads();

    // ---- Gram via MFMA: G = Zs^H Zs (48x48, K=512). Wave wv owns 16-col strip.
    //      Hermitian: keep only upper triangle (col >= m) incl. RHS cols 40..47. ----
    int wv = tid >> 6, ln = tid & 63;
    int kg = ln >> 4;            // 16-lane group (k-slice selector for MFMA frags)
    if (wv < 3) {
        int r16 = ln & 15;
        int offB = zs_off(wv * 16 + r16);
#pragma unroll 1
        for (int mt = 0; mt < 3; ++mt) {
            int offA = zs_off(mt * 16 + r16);
            floatx4 aRe = {0.f, 0.f, 0.f, 0.f};
            floatx4 aIm = {0.f, 0.f, 0.f, 0.f};
#pragma unroll 2
            for (int ks = 0; ks < 16; ++ks) {
                int kbase = ks * 32 + kg * 8;
                uint32x4 sv = *(const uint32x4*)&sw_pk[kbase >> 1];
                Frag B = build2(&sYh[offB + kbase], sv[0], sv[1], sv[2], sv[3]);
                Frag A = build2(&sYh[offA + kbase], sv[0], sv[1], sv[2], sv[3]);
                half8 nYa = -A.Y;
                aRe = __builtin_amdgcn_mfma_f32_16x16x32_f16(A.X, B.X, aRe, 0, 0, 0);
                aRe = __builtin_amdgcn_mfma_f32_16x16x32_f16(A.Y, B.Y, aRe, 0, 0, 0);
                aIm = __builtin_amdgcn_mfma_f32_16x16x32_f16(A.X, B.Y, aIm, 0, 0, 0);
                aIm = __builtin_amdgcn_mfma_f32_16x16x32_f16(nYa, B.X, aIm, 0, 0, 0);
            }
            // C/D layout: col = lane&15, row = (lane>>4)*4 + reg  [m89-verified]
#pragma unroll
            for (int r = 0; r < 4; ++r) {
                int m = mt * 16 + kg * 4 + r;
                int col = wv * 16 + r16;
                if (m < N_ && col >= m)
                    sAugU[rowoff(m) + col - m] = make_float2(aRe[r], aIm[r]);
            }
        }
    }
    __syncthreads();

    // ---- diag loading: wave-parallel trace reduce ----
    if (tid < 64) {
        float dv = (tid < N_) ? sAugU[rowoff(tid)].x : 0.f;
#pragma unroll
        for (int off = 32; off; off >>= 1) dv += __shfl_xor(dv, off, 64);
        if (tid < N_) sAugU[rowoff(tid)].x += 1e-10f * dv / N_;
    }
    __syncthreads();

    // ---- forward elimination on packed upper triangle (Hermitian, half work).
    //      m_i = conj(A[p][i]) * inv_p  ==  A[i][p] * inv_p  exactly. ----
    {
        int ri = tid >> 4, ci = tid & 15;
#pragma unroll 1
        for (int p = 0; p < N_ - 1; ++p) {
            int rop = rowoff(p);
            float2 piv = sAugU[rop];
            float dnm = piv.x * piv.x + piv.y * piv.y;
            float pix = piv.x / dnm, piy = -piv.y / dnm;
#pragma unroll 1
            for (int i = p + 1 + ri; i < N_; i += 16) {
                float2 api = sAugU[rop + i - p];       // A[p][i]
                float mx = api.x * pix + api.y * piy;  // conj(api)*inv
                float my = api.x * piy - api.y * pix;
                int roi = rowoff(i) - i;               // + j gives addr
#pragma unroll 1
                for (int j = i + ci; j < NA; j += 16) {
                    float2 apj = sAugU[rop + j - p];
                    float2 v = sAugU[roi + j];
                    v.x -= mx * apj.x - my * apj.y;
                    v.y -= mx * apj.y + my * apj.x;
                    sAugU[roi + j] = v;
                }
            }
            __syncthreads();
        }
    }
    // ---- backward elimination on RHS columns (i<p reads (i,p): upper ✓) ----
    {
        int bc = tid & 7, br = tid >> 3;
#pragma unroll 1
        for (int p = N_ - 1; p > 0; --p) {
            int rop = rowoff(p);
            float2 piv = sAugU[rop];
            float dnm = piv.x * piv.x + piv.y * piv.y;
            float pix = piv.x / dnm, piy = -piv.y / dnm;
            float2 rhs = sAugU[rop + N_ + bc - p];
            float xr = rhs.x * pix - rhs.y * piy;
            float xi = rhs.x * piy + rhs.y * pix;
#pragma unroll 1
            for (int i = br; i < p; i += 32) {
                int roi = rowoff(i) - i;
                float2 aip = sAugU[roi + p];
                float2 v = sAugU[roi + N_ + bc];
                v.x -= aip.x * xr - aip.y * xi;
                v.y -= aip.x * xi + aip.y * xr;
                sAugU[roi + N_ + bc] = v;
            }
            __syncthreads();
        }
    }
    // ---- G, transposed store: sGT[e][d][tau] = RHS[j=tau*8+d][e] / diag[j].
    //      sGT overlays sPow (dead since weights phase). ----
    for (int idx = tid; idx < N_ * C_; idx += 256) {
        int j = idx >> 3;
        int e = idx & 7;
        int roj = rowoff(j);
        float2 piv = sAugU[roj];
        float dnm = piv.x * piv.x + piv.y * piv.y;
        float pix = piv.x / dnm, piy = -piv.y / dnm;
        float2 rhs = sAugU[roj + N_ + e - j];
        int tau = j >> 3, d = j & 7;
        sGT[(e * C_ + d) * TAPS + tau] =
            make_float2(rhs.x * pix - rhs.y * piy, rhs.x * piy + rhs.y * pix);
    }
    __syncthreads();   // sAugU dead from here -> reuse as zBuf

    // ================= MFMA tail, 4-wave =================
    // tail[e][t] = sum_j G[j][e] * Zraw[j][t]. 64-t chunks; ONE shared z-plane
    // [64][ZSD] (9216 B) used twice per chunk: build RE -> MFMA(Br) -> build IM
    // -> MFMA(Bi), accR/accI accumulating across both passes (complex product
    // identical to R9/R10). All 4 waves compute (wave wv owns t-subtile wv);
    // R10 had waves 2-3 idle through the whole tail. Direct term from LDS f16
    // (adds <=~3e-3 vs 0.134 threshold; removes 4096 scattered loads/block).
    uint32_t* zBuf = (uint32_t*)sAugU;               // [64][ZSD] dwords (f16 pairs)
    half8 aFr[2], aFi[2];
    {
        int m = ln & 15;
#pragma unroll
        for (int ks = 0; ks < 2; ++ks) {
            half8 hr = {}, hi = {};
#pragma unroll
            for (int q = 0; q < 8; ++q) {
                int j = ks * 32 + kg * 8 + q;
                float gx = 0.f, gy = 0.f;
                if (m < 8 && j < N_) {
                    float2 g = sGT[(m * C_ + (j & 7)) * TAPS + (j >> 3)];
                    gx = g.x; gy = g.y;
                }
                hr[q] = (_Float16)gx;
                hi[q] = (_Float16)gy;
            }
            aFr[ks] = hr;
            aFi[ks] = hi;
        }
    }
    // zero the plane once (covers k-pad j>=40: builds only write jp<20)
    for (int idx = tid; idx < 64 * ZSD; idx += 256) zBuf[idx] = 0;
    __syncthreads();

    int trow = wv * 16 + (ln & 15);   // this thread's t within the 64-t chunk
#pragma unroll 1
    for (int ch = 0; ch < 8; ++ch) {
        int c0 = ch * 64;
        // ---- build RE plane: 20 j-pairs x 64 t (taus 8-aligned: pairs never
        //      cross a tau boundary). sYh idx = t -3-tau + YPAD; pad drops s<0.
        for (int idx = tid; idx < 1280; idx += 256) {
            int jp = idx >> 6, tl = idx & 63;
            int j0 = 2 * jp, j1 = j0 + 1;
            int base = c0 + tl + (YPAD - 3);
            uint32_t y0 = sYh[(j0 & 7) * YSH + base - (j0 >> 3)];
            uint32_t y1 = sYh[(j1 & 7) * YSH + base - (j1 >> 3)];
            zBuf[tl * ZSD + jp] = __builtin_amdgcn_perm(y1, y0, 0x05040100);
        }
        __syncthreads();
        floatx4 accR = {0.f, 0.f, 0.f, 0.f};
        floatx4 accI = {0.f, 0.f, 0.f, 0.f};
#pragma unroll
        for (int ks = 0; ks < 2; ++ks) {
            int o = trow * ZSD + ks * 16 + kg * 4;
            half8 Br = __builtin_bit_cast(half8, *(const uint32x4*)&zBuf[o]);
            accR = __builtin_amdgcn_mfma_f32_16x16x32_f16(aFr[ks], Br, accR, 0, 0, 0);
            accI = __builtin_amdgcn_mfma_f32_16x16x32_f16(aFi[ks], Br, accI, 0, 0, 0);
        }
        __syncthreads();   // WAR: IM build overwrites zBuf
        // ---- build IM plane ----
        for (int idx = tid; idx < 1280; idx += 256) {
            int jp = idx >> 6, tl = idx & 63;
            int j0 = 2 * jp, j1 = j0 + 1;
            int base = c0 + tl + (YPAD - 3);
            uint32_t y0 = sYh[(j0 & 7) * YSH + base - (j0 >> 3)];
            uint32_t y1 = sYh[(j1 & 7) * YSH + base - (j1 >> 3)];
            zBuf[tl * ZSD + jp] = __builtin_amdgcn_perm(y1, y0, 0x07060302);
        }
        __syncthreads();
#pragma unroll
        for (int ks = 0; ks < 2; ++ks) {
            int o = trow * ZSD + ks * 16 + kg * 4;
            half8 Bi = __builtin_bit_cast(half8, *(const uint32x4*)&zBuf[o]);
            half8 nFi = -aFi[ks];
            accR = __builtin_amdgcn_mfma_f32_16x16x32_f16(nFi, Bi, accR, 0, 0, 0);
            accI = __builtin_amdgcn_mfma_f32_16x16x32_f16(aFr[ks], Bi, accI, 0, 0, 0);
        }
        // ---- stores: D rows kg*4+r = e in [0,8); direct term from LDS f16.
        //      Issued before the barrier (global stores don't block; no zBuf
        //      hazard - they read only sYh). ----
        if (kg < 2) {
            int tg = c0 + trow;
            bool dead = (tg >= ilen);
#pragma unroll
            for (int r = 0; r < 4; ++r) {
                int e = kg * 4 + r;
                float2 cf = unpackf16(sYh[e * YSH + YPAD + tg]);
                float ex = cf.x - accR[r];
                float ey = cf.y - accI[r];
                if (dead) { ex = 0.f; ey = 0.f; }
                size_t o = (size_t)b * T_ * C_ * F_ + ((size_t)tg * C_ + e) * F_ + f;
                out_re[o] = ex;
                out_im[o] = ey;
            }
        }
        __syncthreads();   // WAR: next chunk's RE build overwrites zBuf
    }
}

extern "C" void kernel_launch(void* const* d_in, const int* in_sizes, int n_in,
                              void* d_out, int out_size, void* d_ws, size_t ws_size,
                              hipStream_t stream) {
    const float* in_re = (const float*)d_in[0];
    const float* in_im = (const float*)d_in[1];
    const int* ilens = (const int*)d_in[2];

    float* out_re = (float*)d_out;
    float* out_im = out_re + BTCF;
    float* out_pw = out_im + BTCF;   // (B,F,T) float32

    // Single fused kernel: no transposes, no workspace.
    k_fused<<<BF, 256, 0, stream>>>(in_re, in_im, ilens, out_re, out_im, out_pw);
}

// Round 12
// 188.253 us; speedup vs baseline: 1.1179x; 1.0059x over previous
//
#include <hip/hip_runtime.h>
#include <hip/hip_fp16.h>

// Problem constants (fixed shapes from setup_inputs)
#define B_ 4
#define T_ 512
#define C_ 8
#define F_ 257
#define TAPS 5
#define DELAY 3
#define N_ 40          // TAPS*C
#define NA 48          // N_ + C_ (augmented: R | P)
#define TP 505         // T - DELAY - TAPS + 1
#define T0 7           // DELAY + TAPS - 1
#define BF (B_*F_)     // 1028
#define BTCF ((size_t)B_*T_*C_*F_)
#define YSH 532        // padded LDS row stride (f16x2 dwords)
#define YPAD 8         // leading zero pad (t stored at index t+YPAD)
#define ZSD 20         // z-plane dword stride per t-row (40 f16 = 20 dwords, 80B: 16B-aligned)

typedef _Float16 half8 __attribute__((ext_vector_type(8)));
typedef float floatx4 __attribute__((ext_vector_type(4)));
typedef uint32_t uint32x4 __attribute__((ext_vector_type(4)));

__device__ inline uint32_t h2mul(uint32_t a, uint32_t b) {
    __half2 r = __hmul2(__builtin_bit_cast(__half2, a), __builtin_bit_cast(__half2, b));
    return __builtin_bit_cast(uint32_t, r);
}
__device__ inline uint32_t packf16(float2 v) {
    __half2 h = __floats2half2_rn(v.x, v.y);
    return __builtin_bit_cast(uint32_t, h);
}
__device__ inline float2 unpackf16(uint32_t u) {
    __half2 h = __builtin_bit_cast(__half2, u);
    return make_float2(__low2float(h), __high2float(h));
}
__device__ inline half8 mkfrag(uint32_t a, uint32_t b, uint32_t c, uint32_t d) {
    uint32x4 v = {a, b, c, d};
    return __builtin_bit_cast(half8, v);
}
// packed upper-triangle row start: row i holds cols i..47 (+1 pad) -> 49-i entries
__device__ inline int rowoff(int i) {
    return i * 49 - ((i * (i - 1)) >> 1);
}

struct Frag { half8 X; half8 Y; };

// Build weighted re (X) / im (Y) f16 fragments from 8 consecutive interleaved
// f16x2 dwords at p, scaled by packed f16 weight pairs sw0..3. Pure value flow.
__device__ inline Frag build2(const uint32_t* p, uint32_t sw0, uint32_t sw1,
                              uint32_t sw2, uint32_t sw3) {
    uint32_t q0 = p[0], q1 = p[1], q2 = p[2], q3 = p[3];
    uint32_t q4 = p[4], q5 = p[5], q6 = p[6], q7 = p[7];
    uint32_t x0 = __builtin_amdgcn_perm(q1, q0, 0x05040100);
    uint32_t y0 = __builtin_amdgcn_perm(q1, q0, 0x07060302);
    uint32_t x1 = __builtin_amdgcn_perm(q3, q2, 0x05040100);
    uint32_t y1 = __builtin_amdgcn_perm(q3, q2, 0x07060302);
    uint32_t x2 = __builtin_amdgcn_perm(q5, q4, 0x05040100);
    uint32_t y2 = __builtin_amdgcn_perm(q5, q4, 0x07060302);
    uint32_t x3 = __builtin_amdgcn_perm(q7, q6, 0x05040100);
    uint32_t y3 = __builtin_amdgcn_perm(q7, q6, 0x07060302);
    Frag f;
    f.X = mkfrag(h2mul(x0, sw0), h2mul(x1, sw1), h2mul(x2, sw2), h2mul(x3, sw3));
    f.Y = mkfrag(h2mul(y0, sw0), h2mul(y1, sw1), h2mul(y2, sw2), h2mul(y3, sw3));
    return f;
}
// Zs row j -> dword offset into sYh (t stored at t+YPAD):
// j<40: tap=j>>3,c=j&7 -> Y[c][k+4-tap]; j>=40: Y[j-40][k+7]
__device__ inline int zs_off(int j) {
    return (j < N_) ? (j & 7) * YSH + (YPAD + 4 - (j >> 3)) : (j - N_) * YSH + (YPAD + T0);
}

// ---------------- Fully fused single kernel. R12: barrier-count attack.
// R11 counters: 64MB @ 8% peak BW, VALUBusy 45% -> per-block latency 307k cyc
// over ~117 barrier phases ~ 2600 cyc/phase: BARRIER-LATENCY-BOUND.
// (1) two-pivot fwd/bwd elimination: 39+39 -> 20+20 intervals. All reads are
//     pre-interval values; row-(p+1) update recomputed on the fly and its
//     write DEFERRED one interval (regs); algebra == two sequential pivots
//     up to O(ulp) (MFMA diag imag is exactly 0).
// (2) tail: both z-planes resident (stride 20, 2x5120B in pool) -> one build
//     pass, 2 barriers/chunk (was 4), no zero-fill; ks=1 B-frags loaded only
//     by kg==0 lanes (j 32..39), others exact zero.
__global__ __launch_bounds__(256) void k_fused(const float* __restrict__ in_re,
                                               const float* __restrict__ in_im,
                                               const int* __restrict__ ilens,
                                               float* __restrict__ out_re,
                                               float* __restrict__ out_im,
                                               float* __restrict__ pow_out) {
    __shared__ uint32_t sYh[C_ * YSH];               // 17024 B f16x2, t at t+YPAD
    __shared__ __align__(16) uint32_t pool[3256];    // 13024 B, multi-phase carve:
    // bytes 0..2560:   sPow[512] f32 (stage->weights), then sGT[320] f2 (G->A-frags)
    // bytes 2560..3584: sw_pk[256] (weights->Gram)
    // bytes 3584..13024: sAugU[1180] f2 packed upper tri (Gram->G)
    // tail: zRe = pool[0..1280), zIm = pool[1280..2560) dwords ([64][ZSD] each)
    float* sPow = (float*)pool;
    float2* sGT = (float2*)pool;
    uint32_t* sw_pk = pool + 640;
    float2* sAugU = (float2*)(pool + 896);
    int tid = threadIdx.x;

    // ---- XCD-grouped bijective block swizzle (R10-proven line sharing) ----
    int bid = blockIdx.x;
    int xcd = bid & 7, slot = bid >> 3;
    int w = (xcd < 4) ? xcd * 129 + slot : 516 + (xcd - 4) * 128 + slot;
    int b = w / F_;                 // magic-mul (constant divisor)
    int f = w - b * F_;
    int ilen = ilens[b];
    const float* pre = in_re + (size_t)b * T_ * C_ * F_ + f;
    const float* pim = in_im + (size_t)b * T_ * C_ * F_ + f;

    // ---- stage: planar scalar 4B reads, f16x2 LDS writes, fp32 power ----
    {
        int t0 = tid, t1 = tid + 256;
        float s0 = 0.f, s1 = 0.f;
#pragma unroll 4
        for (int c = 0; c < C_; ++c) {
            size_t a0 = ((size_t)t0 * C_ + c) * F_;
            size_t a1 = ((size_t)t1 * C_ + c) * F_;
            float xr0 = pre[a0], xi0 = pim[a0];
            float xr1 = pre[a1], xi1 = pim[a1];
            sYh[c * YSH + YPAD + t0] = packf16(make_float2(xr0, xi0));
            sYh[c * YSH + YPAD + t1] = packf16(make_float2(xr1, xi1));
            s0 += xr0 * xr0 + xi0 * xi0;
            s1 += xr1 * xr1 + xi1 * xi1;
        }
        if (tid < 20) {
            int z = (tid < 8) ? tid : (512 + tid);   // [0..7] and [520..531]
#pragma unroll
            for (int c = 0; c < C_; ++c) sYh[c * YSH + z] = 0;
        }
        s0 = fmaxf(s0 * (1.0f / C_), 1e-6f);
        s1 = fmaxf(s1 * (1.0f / C_), 1e-6f);
        pow_out[(size_t)w * T_ + t0] = s0;           // (B,F,T), coalesced
        pow_out[(size_t)w * T_ + t1] = s1;
        sPow[t0] = s0;
        sPow[t1] = s1;
    }
    __syncthreads();

    // ---- packed f16 sqrt(1/p[k+7]) weight pairs; zero for k >= TP ----
    {
        int k0 = 2 * tid, k1 = k0 + 1;
        float w0 = (k0 < TP) ? rsqrtf(sPow[k0 + T0]) : 0.f;   // p >= 1e-6
        float w1 = (k1 < TP) ? rsqrtf(sPow[k1 + T0]) : 0.f;
        sw_pk[tid] = packf16(make_float2(w0, w1));
    }
    __syncthreads();

    // ---- Gram via MFMA: G = Zs^H Zs (48x48, K=512), Hermitian upper only ----
    int wv = tid >> 6, ln = tid & 63;
    int kg = ln >> 4;
    if (wv < 3) {
        int r16 = ln & 15;
        int offB = zs_off(wv * 16 + r16);
#pragma unroll 1
        for (int mt = 0; mt < 3; ++mt) {
            int offA = zs_off(mt * 16 + r16);
            floatx4 aRe = {0.f, 0.f, 0.f, 0.f};
            floatx4 aIm = {0.f, 0.f, 0.f, 0.f};
#pragma unroll 2
            for (int ks = 0; ks < 16; ++ks) {
                int kbase = ks * 32 + kg * 8;
                uint32x4 sv = *(const uint32x4*)&sw_pk[kbase >> 1];
                Frag B = build2(&sYh[offB + kbase], sv[0], sv[1], sv[2], sv[3]);
                Frag A = build2(&sYh[offA + kbase], sv[0], sv[1], sv[2], sv[3]);
                half8 nYa = -A.Y;
                aRe = __builtin_amdgcn_mfma_f32_16x16x32_f16(A.X, B.X, aRe, 0, 0, 0);
                aRe = __builtin_amdgcn_mfma_f32_16x16x32_f16(A.Y, B.Y, aRe, 0, 0, 0);
                aIm = __builtin_amdgcn_mfma_f32_16x16x32_f16(A.X, B.Y, aIm, 0, 0, 0);
                aIm = __builtin_amdgcn_mfma_f32_16x16x32_f16(nYa, B.X, aIm, 0, 0, 0);
            }
            // C/D layout: col = lane&15, row = (lane>>4)*4 + reg  [m89-verified]
#pragma unroll
            for (int r = 0; r < 4; ++r) {
                int m = mt * 16 + kg * 4 + r;
                int col = wv * 16 + r16;
                if (m < N_ && col >= m)
                    sAugU[rowoff(m) + col - m] = make_float2(aRe[r], aIm[r]);
            }
        }
    }
    __syncthreads();

    // ---- diag loading: wave-parallel trace reduce ----
    if (tid < 64) {
        float dv = (tid < N_) ? sAugU[rowoff(tid)].x : 0.f;
#pragma unroll
        for (int off = 32; off; off >>= 1) dv += __shfl_xor(dv, off, 64);
        if (tid < N_) sAugU[rowoff(tid)].x += 1e-10f * dv / N_;
    }
    __syncthreads();

    // ---- forward elimination, TWO pivots (p,q=p+1) per barrier interval.
    //      All reads are pre-interval values; row q's single-pivot update is
    //      recomputed on the fly by consumers and its write deferred one
    //      interval (held in dq0..dq2 by the 16 ri==0 threads). Next interval
    //      reads rows p+2,p+3 + own rows only -> no conflict with the flush. ----
    {
        int ri = tid >> 4, ci = tid & 15;
        float2 dq0, dq1, dq2;
#pragma unroll 1
        for (int p = 0; p < N_ - 2; p += 2) {
            if (p > 0 && ri == 0) {          // flush deferred row p-1
                int qm = p - 1, roqm = rowoff(qm);
                if (ci < NA - qm)      sAugU[roqm + ci] = dq0;
                if (ci + 16 < NA - qm) sAugU[roqm + ci + 16] = dq1;
                if (ci + 32 < NA - qm) sAugU[roqm + ci + 32] = dq2;
            }
            int q = p + 1;
            int rop = rowoff(p), roq = rowoff(q);
            float2 Upp = sAugU[rop];
            float2 Upq = sAugU[rop + 1];
            float2 Uqq = sAugU[roq];
            float dn0 = Upp.x * Upp.x + Upp.y * Upp.y;
            float i0x = Upp.x / dn0, i0y = -Upp.y / dn0;
            float mqx = Upq.x * i0x + Upq.y * i0y;     // m0q = conj(Upq)*inv0
            float mqy = Upq.x * i0y - Upq.y * i0x;
            float d1x = Uqq.x - (mqx * Upq.x - mqy * Upq.y);   // U1[q][q]
            float d1y = Uqq.y - (mqx * Upq.y + mqy * Upq.x);
            float dn1 = d1x * d1x + d1y * d1y;
            float i1x = d1x / dn1, i1y = -d1y / dn1;
#pragma unroll 1
            for (int i = q + ri; i < N_; i += 16) {
                if (i == q) {                 // row q -> regs (deferred write)
#pragma unroll
                    for (int s = 0; s < 3; ++s) {
                        int j = q + ci + 16 * s;
                        float2 r = make_float2(0.f, 0.f);
                        if (j < NA) {
                            float2 Upj = sAugU[rop + j - p];
                            float2 Uqj = sAugU[roq + j - q];
                            r.x = Uqj.x - (mqx * Upj.x - mqy * Upj.y);
                            r.y = Uqj.y - (mqx * Upj.y + mqy * Upj.x);
                        }
                        if (s == 0) dq0 = r; else if (s == 1) dq1 = r; else dq2 = r;
                    }
                } else {                      // rows i>=p+2: double update
                    float2 Upi = sAugU[rop + i - p];
                    float m0x = Upi.x * i0x + Upi.y * i0y;     // conj(Upi)*inv0
                    float m0y = Upi.x * i0y - Upi.y * i0x;
                    float2 Uqi = sAugU[roq + i - q];
                    float ax = Uqi.x - (m0x * Upq.x - m0y * Upq.y);   // A1[i][q]
                    float ay = -Uqi.y - (m0x * Upq.y + m0y * Upq.x);
                    float m1x = ax * i1x - ay * i1y;           // m1 = a*inv1
                    float m1y = ax * i1y + ay * i1x;
                    int roi = rowoff(i) - i;
#pragma unroll 1
                    for (int j = i + ci; j < NA; j += 16) {
                        float2 Upj = sAugU[rop + j - p];
                        float2 Uqj = sAugU[roq + j - q];
                        float u1x = Uqj.x - (mqx * Upj.x - mqy * Upj.y);
                        float u1y = Uqj.y - (mqx * Upj.y + mqy * Upj.x);
                        float2 v = sAugU[roi + j];
                        v.x -= (m0x * Upj.x - m0y * Upj.y) + (m1x * u1x - m1y * u1y);
                        v.y -= (m0x * Upj.y + m0y * Upj.x) + (m1x * u1y + m1y * u1x);
                        sAugU[roi + j] = v;
                    }
                }
            }
            __syncthreads();
        }
        // final single pivot p=38 (+ flush deferred row 37; p=38 reads rows 38,39 only)
        {
            int p = N_ - 2;
            if (ri == 0) {
                int qm = p - 1, roqm = rowoff(qm);
                if (ci < NA - qm)      sAugU[roqm + ci] = dq0;
                if (ci + 16 < NA - qm) sAugU[roqm + ci + 16] = dq1;
                if (ci + 32 < NA - qm) sAugU[roqm + ci + 32] = dq2;
            }
            int rop = rowoff(p);
            float2 piv = sAugU[rop];
            float dn = piv.x * piv.x + piv.y * piv.y;
            float px = piv.x / dn, py = -piv.y / dn;
#pragma unroll 1
            for (int i = p + 1 + ri; i < N_; i += 16) {
                float2 api = sAugU[rop + i - p];
                float mx = api.x * px + api.y * py;
                float my = api.x * py - api.y * px;
                int roi = rowoff(i) - i;
#pragma unroll 1
                for (int j = i + ci; j < NA; j += 16) {
                    float2 apj = sAugU[rop + j - p];
                    float2 v = sAugU[roi + j];
                    v.x -= mx * apj.x - my * apj.y;
                    v.y -= mx * apj.y + my * apj.x;
                    sAugU[roi + j] = v;
                }
            }
            __syncthreads();
        }
    }
    // ---- backward elimination on RHS, TWO pivots (p,q=p-1) per interval.
    //      x_q derived from pre-interval rhs[q]; row q's rhs write deferred. ----
    {
        int bc = tid & 7, br = tid >> 3;
        float2 defv = make_float2(0.f, 0.f);
        int defRow = -1;
#pragma unroll 1
        for (int p = N_ - 1; p >= 3; p -= 2) {
            if (defRow >= 0 && br == (defRow & 31))
                sAugU[rowoff(defRow) + N_ + bc - defRow] = defv;
            int q = p - 1;
            int rop = rowoff(p), roq = rowoff(q);
            float2 pivP = sAugU[rop];
            float dnP = pivP.x * pivP.x + pivP.y * pivP.y;
            float pPx = pivP.x / dnP, pPy = -pivP.y / dnP;
            float2 rhsP = sAugU[rop + N_ + bc - p];
            float xPx = rhsP.x * pPx - rhsP.y * pPy;
            float xPy = rhsP.x * pPy + rhsP.y * pPx;
            float2 pivQ = sAugU[roq];
            float dnQ = pivQ.x * pivQ.x + pivQ.y * pivQ.y;
            float pQx = pivQ.x / dnQ, pQy = -pivQ.y / dnQ;
            float2 Uqp = sAugU[roq + 1];                 // U[p-1][p]
            float2 rhsQ = sAugU[roq + N_ + bc - q];
            float rqx = rhsQ.x - (Uqp.x * xPx - Uqp.y * xPy);   // rhs'[q]
            float rqy = rhsQ.y - (Uqp.x * xPy + Uqp.y * xPx);
            float xQx = rqx * pQx - rqy * pQy;
            float xQy = rqx * pQy + rqy * pQx;
#pragma unroll 1
            for (int i = br; i <= p - 2; i += 32) {
                int roi = rowoff(i) - i;
                float2 Uip = sAugU[roi + p];
                float2 Uiq = sAugU[roi + q];
                float2 v = sAugU[roi + N_ + bc];
                v.x -= (Uip.x * xPx - Uip.y * xPy) + (Uiq.x * xQx - Uiq.y * xQy);
                v.y -= (Uip.x * xPy + Uip.y * xPx) + (Uiq.x * xQy + Uiq.y * xQx);
                sAugU[roi + N_ + bc] = v;
            }
            if (br == (q & 31)) defv = make_float2(rqx, rqy);
            defRow = q;
            __syncthreads();
        }
        // single pivot p=1 (+ flush deferred rhs row 2)
        {
            if (defRow >= 0 && br == (defRow & 31))
                sAugU[rowoff(defRow) + N_ + bc - defRow] = defv;
            int rop = rowoff(1);
            float2 piv = sAugU[rop];
            float dn = piv.x * piv.x + piv.y * piv.y;
            float px = piv.x / dn, py = -piv.y / dn;
            float2 rhs = sAugU[rop + N_ + bc - 1];
            float xr = rhs.x * px - rhs.y * py;
            float xi = rhs.x * py + rhs.y * px;
            if (br == 0) {
                float2 aip = sAugU[1];                   // U[0][1] (rowoff(0)=0)
                float2 v = sAugU[N_ + bc];               // rhs[0]
                v.x -= aip.x * xr - aip.y * xi;
                v.y -= aip.x * xi + aip.y * xr;
                sAugU[N_ + bc] = v;
            }
            __syncthreads();
        }
    }
    // ---- G, transposed store: sGT[e][d][tau] = RHS[j]/diag[j] (overlays sPow) ----
    for (int idx = tid; idx < N_ * C_; idx += 256) {
        int j = idx >> 3;
        int e = idx & 7;
        int roj = rowoff(j);
        float2 piv = sAugU[roj];
        float dnm = piv.x * piv.x + piv.y * piv.y;
        float pix = piv.x / dnm, piy = -piv.y / dnm;
        float2 rhs = sAugU[roj + N_ + e - j];
        int tau = j >> 3, d = j & 7;
        sGT[(e * C_ + d) * TAPS + tau] =
            make_float2(rhs.x * pix - rhs.y * piy, rhs.x * piy + rhs.y * pix);
    }
    __syncthreads();

    // ---- A fragments from sGT (f16 cast; G ~O(1), threshold 0.134) ----
    half8 aFr[2], aFi[2];
    {
        int m = ln & 15;
#pragma unroll
        for (int ks = 0; ks < 2; ++ks) {
            half8 hr = {}, hi = {};
#pragma unroll
            for (int q = 0; q < 8; ++q) {
                int j = ks * 32 + kg * 8 + q;
                float gx = 0.f, gy = 0.f;
                if (m < 8 && j < N_) {
                    float2 g = sGT[(m * C_ + (j & 7)) * TAPS + (j >> 3)];
                    gx = g.x; gy = g.y;
                }
                hr[q] = (_Float16)gx;
                hi[q] = (_Float16)gy;
            }
            aFr[ks] = hr;
            aFi[ks] = hi;
        }
    }
    __syncthreads();   // sGT reads done -> pool becomes zRe/zIm planes

    // ================= MFMA tail, both planes resident =================
    // tail[e][t] = sum_j G[j][e]*Zraw[j][t]. 64-t chunks, 2 barriers each:
    // one build pass writes BOTH planes (rows fully covered, no zero-fill);
    // ks=1 covers j=32..39 -> only kg==0 lanes load, others contribute 0.
    uint32_t* zRe = pool;                    // [64][ZSD]
    uint32_t* zIm = pool + 64 * ZSD;         // [64][ZSD]
    int trow = wv * 16 + (ln & 15);
#pragma unroll 1
    for (int ch = 0; ch < 8; ++ch) {
        int c0 = ch * 64;
        for (int idx = tid; idx < 1280; idx += 256) {
            int jp = idx >> 6, tl = idx & 63;
            int j0 = 2 * jp, j1 = j0 + 1;
            int base = c0 + tl + (YPAD - 3);
            uint32_t y0 = sYh[(j0 & 7) * YSH + base - (j0 >> 3)];
            uint32_t y1 = sYh[(j1 & 7) * YSH + base - (j1 >> 3)];
            zRe[tl * ZSD + jp] = __builtin_amdgcn_perm(y1, y0, 0x05040100);
            zIm[tl * ZSD + jp] = __builtin_amdgcn_perm(y1, y0, 0x07060302);
        }
        __syncthreads();
        floatx4 accR = {0.f, 0.f, 0.f, 0.f};
        floatx4 accI = {0.f, 0.f, 0.f, 0.f};
        {
            int o0 = trow * ZSD + kg * 4;
            half8 Br0 = __builtin_bit_cast(half8, *(const uint32x4*)&zRe[o0]);
            half8 Bi0 = __builtin_bit_cast(half8, *(const uint32x4*)&zIm[o0]);
            half8 Br1 = {}, Bi1 = {};
            if (kg == 0) {
                int o1 = trow * ZSD + 16;
                Br1 = __builtin_bit_cast(half8, *(const uint32x4*)&zRe[o1]);
                Bi1 = __builtin_bit_cast(half8, *(const uint32x4*)&zIm[o1]);
            }
            half8 nFi0 = -aFi[0], nFi1 = -aFi[1];
            accR = __builtin_amdgcn_mfma_f32_16x16x32_f16(aFr[0], Br0, accR, 0, 0, 0);
            accR = __builtin_amdgcn_mfma_f32_16x16x32_f16(aFr[1], Br1, accR, 0, 0, 0);
            accI = __builtin_amdgcn_mfma_f32_16x16x32_f16(aFi[0], Br0, accI, 0, 0, 0);
            accI = __builtin_amdgcn_mfma_f32_16x16x32_f16(aFi[1], Br1, accI, 0, 0, 0);
            accR = __builtin_amdgcn_mfma_f32_16x16x32_f16(nFi0, Bi0, accR, 0, 0, 0);
            accR = __builtin_amdgcn_mfma_f32_16x16x32_f16(nFi1, Bi1, accR, 0, 0, 0);
            accI = __builtin_amdgcn_mfma_f32_16x16x32_f16(aFr[0], Bi0, accI, 0, 0, 0);
            accI = __builtin_amdgcn_mfma_f32_16x16x32_f16(aFr[1], Bi1, accI, 0, 0, 0);
        }
        // stores: D rows kg*4+r = e in [0,8); direct term from LDS f16; reads
        // only sYh (no plane hazard) so issue before the barrier.
        if (kg < 2) {
            int tg = c0 + trow;
            bool dead = (tg >= ilen);
#pragma unroll
            for (int r = 0; r < 4; ++r) {
                int e = kg * 4 + r;
                float2 cf = unpackf16(sYh[e * YSH + YPAD + tg]);
                float ex = cf.x - accR[r];
                float ey = cf.y - accI[r];
                if (dead) { ex = 0.f; ey = 0.f; }
                size_t o = (size_t)b * T_ * C_ * F_ + ((size_t)tg * C_ + e) * F_ + f;
                out_re[o] = ex;
                out_im[o] = ey;
            }
        }
        __syncthreads();   // WAR: next chunk's build overwrites planes
    }
}

extern "C" void kernel_launch(void* const* d_in, const int* in_sizes, int n_in,
                              void* d_out, int out_size, void* d_ws, size_t ws_size,
                              hipStream_t stream) {
    const float* in_re = (const float*)d_in[0];
    const float* in_im = (const float*)d_in[1];
    const int* ilens = (const int*)d_in[2];

    float* out_re = (float*)d_out;
    float* out_im = out_re + BTCF;
    float* out_pw = out_im + BTCF;   // (B,F,T) float32

    // Single fused kernel: no transposes, no workspace.
    k_fused<<<BF, 256, 0, stream>>>(in_re, in_im, ilens, out_re, out_im, out_pw);
}